// Round 11
// baseline (321.398 us; speedup 1.0000x reference)
//
#include <hip/hip_runtime.h>
#include <stdint.h>

typedef unsigned short u16;
typedef __bf16 bfrag __attribute__((ext_vector_type(8)));   // 8 bf16 = 4 VGPRs (MFMA A/B, K=32)
typedef float f32x4 __attribute__((ext_vector_type(4)));    // MFMA C/D

#define LOG2E 1.44269504088896340736f

__device__ __forceinline__ u16 f2bf(float f) {
    unsigned u = __builtin_bit_cast(unsigned, f);
    u = (u + 0x7fffu + ((u >> 16) & 1u)) >> 16;
    return (u16)u;
}
__device__ __forceinline__ float bf2f(u16 x) {
    unsigned u = ((unsigned)x) << 16;
    return __builtin_bit_cast(float, u);
}

__device__ __forceinline__ void gl_lds16(const u16* g, u16* l) {
#if __has_builtin(__builtin_amdgcn_global_load_lds)
    __builtin_amdgcn_global_load_lds(
        (const __attribute__((address_space(1))) unsigned int*)g,
        (__attribute__((address_space(3))) unsigned int*)l, 16, 0, 0);
#else
    *(uint4*)l = *(const uint4*)g;
#endif
}

template <int N>
__device__ __forceinline__ void waitcnt_vm() {
    if constexpr (N == 0)      asm volatile("s_waitcnt vmcnt(0)" ::: "memory");
    else if constexpr (N == 4) asm volatile("s_waitcnt vmcnt(4)" ::: "memory");
    else if constexpr (N == 5) asm volatile("s_waitcnt vmcnt(5)" ::: "memory");
    else if constexpr (N == 6) asm volatile("s_waitcnt vmcnt(6)" ::: "memory");
    else if constexpr (N == 7) asm volatile("s_waitcnt vmcnt(7)" ::: "memory");
    else if constexpr (N == 8) asm volatile("s_waitcnt vmcnt(8)" ::: "memory");
}

// pack 4 f32 -> 2x u32 of bf16 pairs via v_cvt_pk_bf16_f32 (RNE)
__device__ __forceinline__ uint2 pack4(const f32x4& v) {
    uint2 u;
    asm("v_cvt_pk_bf16_f32 %0, %1, %2" : "=v"(u.x) : "v"(v[0]), "v"(v[1]));
    asm("v_cvt_pk_bf16_f32 %0, %1, %2" : "=v"(u.y) : "v"(v[2]), "v"(v[3]));
    return u;
}

// ---------------- fp32 -> bf16 elementwise ----------------
__global__ __launch_bounds__(256) void cvt_f32_bf16(const float* __restrict__ s,
                                                    u16* __restrict__ d, int n4) {
    int i = blockIdx.x * 256 + threadIdx.x;
    if (i < n4) {
        float4 v = ((const float4*)s)[i];
        uint2 o;
        o.x = (unsigned)f2bf(v.x) | ((unsigned)f2bf(v.y) << 16);
        o.y = (unsigned)f2bf(v.z) | ((unsigned)f2bf(v.w) << 16);
        ((uint2*)d)[i] = o;
    }
}

// ---------------- transpose + convert ----------------
__global__ __launch_bounds__(256) void transpose_cvt(const float* __restrict__ src,
                                                     u16* __restrict__ dst,
                                                     int rows, int cols) {
    __shared__ float tile[32][33];
    int c0 = blockIdx.x * 32, r0 = blockIdx.y * 32;
    int tx = threadIdx.x, ty = threadIdx.y;
#pragma unroll
    for (int i = 0; i < 32; i += 8)
        tile[ty + i][tx] = src[(size_t)(r0 + ty + i) * cols + c0 + tx];
    __syncthreads();
#pragma unroll
    for (int i = 0; i < 32; i += 8)
        dst[(size_t)(c0 + ty + i) * rows + r0 + tx] = f2bf(tile[tx][ty + i]);
}

// ---------------- 8-phase 256x256 GEMM (m201-template port): C = A * B^T ------------
// BK=64, 512 thr = 8 waves (2M x 4N), per-wave 128x64 output (acc[8][4]).
// LDS 128 KB: A,B each 2 x (256x64) u16, chunk^(row&7) swizzle (p4-proven, 0 confl).
// Per K-tile t (buf b=t&1), 4 phases, each:
//   {ds_read quadrant subtile -> regs | stage ONE half-tile (2 gl_lds) | vmcnt(4) |
//    barrier | lgkmcnt(0) | setprio(1) 16 MFMA setprio(0) | barrier}
// Quadrants: P1 reads a[mf0-3]+b[nf0-1] -> MFMA m-lo x n-lo; P2 reads b[nf2-3] ->
// m-lo x n-hi; P3 reads a[mf4-7] -> m-hi x n-hi; P4 (regs only) -> m-hi x n-lo.
// Stage stream (derived race-free, write >= 2 barriers after region's last read;
// every half staged >= 3 phases before first read -> resident via vmcnt(4)+barrier):
//   t.P1: A-lo(t+1)->buf^1   (A regions of buf^1 read-free since t-1.P3)
//   t.P2: A-hi(t+1)->buf^1
//   t.P3: B-lo(t+2)->buf     (B regions of buf read-free after t.P2: B read P1,P2 only)
//   t.P4: B-hi(t+2)->buf
// vmcnt(4) leaves exactly the 2 newest stage-pairs in flight; never drains mid-loop.
// Tail (t >= NT-2): vmcnt(0) per phase. Barriers unconditional (block-uniform).
__global__ __launch_bounds__(512, 2) void gemm8(const u16* __restrict__ A,
                                                const u16* __restrict__ B,
                                                u16* __restrict__ C,
                                                int K, int ldc) {
    __shared__ __align__(16) u16 As[2][256 * 64];
    __shared__ __align__(16) u16 Bs[2][256 * 64];
    const int tid = threadIdx.x;
    const int wid = tid >> 6, lane = tid & 63;
    const int quad = lane >> 4, l16 = lane & 15;
    const int wm = wid >> 2, wn = wid & 3;
    const int bm = blockIdx.x * 256, bn = blockIdx.y * 256;
    const int NT = K >> 6;

    // stage source pointers: linear LDS dest chunk c=(j*512+tid) -> inverse-swizzled
    // global source. j=0,1 -> rows 0..127 (lo half), j=2,3 -> rows 128..255 (hi).
    const u16* pA[4];
    const u16* pB[4];
#pragma unroll
    for (int j = 0; j < 4; ++j) {
        int c = j * 512 + tid, row = c >> 3, ch = c & 7;
        pA[j] = A + (size_t)(bm + row) * K + (ch ^ (row & 7)) * 8;
        pB[j] = B + (size_t)(bn + row) * K + (ch ^ (row & 7)) * 8;
    }

    const int swz = l16 & 7;
    const int aBase = (wm * 128 + l16) * 64;
    const int bBase = (wn * 64 + l16) * 64;
    const int c0 = (quad ^ swz) * 8;          // k=0 swizzled chunk offset
    const int c1 = ((4 | quad) ^ swz) * 8;    // k=1

    f32x4 acc[8][4] = {};

    // prologue: tile0 (8 loads) -> buf0; B-lo(1), B-hi(1) (4 loads) -> buf1
#pragma unroll
    for (int j = 0; j < 4; ++j) gl_lds16(pA[j], &As[0][(j * 512 + tid) * 8]);
#pragma unroll
    for (int j = 0; j < 4; ++j) gl_lds16(pB[j], &Bs[0][(j * 512 + tid) * 8]);
#pragma unroll
    for (int j = 0; j < 4; ++j) gl_lds16(pB[j] + 64, &Bs[1][(j * 512 + tid) * 8]);
    waitcnt_vm<4>();
    __builtin_amdgcn_s_barrier();
    asm volatile("" ::: "memory");

    for (int t = 0; t < NT; ++t) {
        const int b = t & 1;
        const u16* ab = &As[b][0];
        const u16* bb = &Bs[b][0];
        const bool g1 = (t + 1 < NT), g2 = (t + 2 < NT);
        const bool tail = (t >= NT - 2);
        const int ko1 = (t + 1) << 6, ko2 = (t + 2) << 6;

        bfrag a[4][2], bl[2][2], bh[2][2];

        // ---- P1: read a(m-lo), b(n-lo) | stage A-lo(t+1) | MFMA m-lo x n-lo ----
#pragma unroll
        for (int mf = 0; mf < 4; ++mf) {
            a[mf][0] = *(const bfrag*)&ab[aBase + mf * 1024 + c0];
            a[mf][1] = *(const bfrag*)&ab[aBase + mf * 1024 + c1];
        }
#pragma unroll
        for (int nf = 0; nf < 2; ++nf) {
            bl[nf][0] = *(const bfrag*)&bb[bBase + nf * 1024 + c0];
            bl[nf][1] = *(const bfrag*)&bb[bBase + nf * 1024 + c1];
        }
        if (g1) {
            gl_lds16(pA[0] + ko1, &As[b ^ 1][(0 * 512 + tid) * 8]);
            gl_lds16(pA[1] + ko1, &As[b ^ 1][(1 * 512 + tid) * 8]);
        }
        if (tail) waitcnt_vm<0>(); else waitcnt_vm<4>();
        __builtin_amdgcn_s_barrier();
        asm volatile("s_waitcnt lgkmcnt(0)" ::: "memory");
        __builtin_amdgcn_s_setprio(1);
#pragma unroll
        for (int mf = 0; mf < 4; ++mf)
#pragma unroll
            for (int nf = 0; nf < 2; ++nf) {
                acc[mf][nf] = __builtin_amdgcn_mfma_f32_16x16x32_bf16(a[mf][0], bl[nf][0], acc[mf][nf], 0, 0, 0);
                acc[mf][nf] = __builtin_amdgcn_mfma_f32_16x16x32_bf16(a[mf][1], bl[nf][1], acc[mf][nf], 0, 0, 0);
            }
        __builtin_amdgcn_s_setprio(0);
        __builtin_amdgcn_s_barrier();
        asm volatile("" ::: "memory");

        // ---- P2: read b(n-hi) | stage A-hi(t+1) | MFMA m-lo x n-hi ----
#pragma unroll
        for (int nf = 0; nf < 2; ++nf) {
            bh[nf][0] = *(const bfrag*)&bb[bBase + (nf + 2) * 1024 + c0];
            bh[nf][1] = *(const bfrag*)&bb[bBase + (nf + 2) * 1024 + c1];
        }
        if (g1) {
            gl_lds16(pA[2] + ko1, &As[b ^ 1][(2 * 512 + tid) * 8]);
            gl_lds16(pA[3] + ko1, &As[b ^ 1][(3 * 512 + tid) * 8]);
        }
        if (tail) waitcnt_vm<0>(); else waitcnt_vm<4>();
        __builtin_amdgcn_s_barrier();
        asm volatile("s_waitcnt lgkmcnt(0)" ::: "memory");
        __builtin_amdgcn_s_setprio(1);
#pragma unroll
        for (int mf = 0; mf < 4; ++mf)
#pragma unroll
            for (int nf = 0; nf < 2; ++nf) {
                acc[mf][nf + 2] = __builtin_amdgcn_mfma_f32_16x16x32_bf16(a[mf][0], bh[nf][0], acc[mf][nf + 2], 0, 0, 0);
                acc[mf][nf + 2] = __builtin_amdgcn_mfma_f32_16x16x32_bf16(a[mf][1], bh[nf][1], acc[mf][nf + 2], 0, 0, 0);
            }
        __builtin_amdgcn_s_setprio(0);
        __builtin_amdgcn_s_barrier();
        asm volatile("" ::: "memory");

        // ---- P3: read a(m-hi) | stage B-lo(t+2) | MFMA m-hi x n-hi ----
#pragma unroll
        for (int mf = 0; mf < 4; ++mf) {
            a[mf][0] = *(const bfrag*)&ab[aBase + (mf + 4) * 1024 + c0];
            a[mf][1] = *(const bfrag*)&ab[aBase + (mf + 4) * 1024 + c1];
        }
        if (g2) {
            gl_lds16(pB[0] + ko2, &Bs[b][(0 * 512 + tid) * 8]);
            gl_lds16(pB[1] + ko2, &Bs[b][(1 * 512 + tid) * 8]);
        }
        if (tail) waitcnt_vm<0>(); else waitcnt_vm<4>();
        __builtin_amdgcn_s_barrier();
        asm volatile("s_waitcnt lgkmcnt(0)" ::: "memory");
        __builtin_amdgcn_s_setprio(1);
#pragma unroll
        for (int mf = 0; mf < 4; ++mf)
#pragma unroll
            for (int nf = 0; nf < 2; ++nf) {
                acc[mf + 4][nf + 2] = __builtin_amdgcn_mfma_f32_16x16x32_bf16(a[mf][0], bh[nf][0], acc[mf + 4][nf + 2], 0, 0, 0);
                acc[mf + 4][nf + 2] = __builtin_amdgcn_mfma_f32_16x16x32_bf16(a[mf][1], bh[nf][1], acc[mf + 4][nf + 2], 0, 0, 0);
            }
        __builtin_amdgcn_s_setprio(0);
        __builtin_amdgcn_s_barrier();
        asm volatile("" ::: "memory");

        // ---- P4: no reads | stage B-hi(t+2) | MFMA m-hi x n-lo (regs only) ----
        if (g2) {
            gl_lds16(pB[2] + ko2, &Bs[b][(2 * 512 + tid) * 8]);
            gl_lds16(pB[3] + ko2, &Bs[b][(3 * 512 + tid) * 8]);
        }
        if (tail) waitcnt_vm<0>(); else waitcnt_vm<4>();
        __builtin_amdgcn_s_barrier();
        asm volatile("" ::: "memory");
        __builtin_amdgcn_s_setprio(1);
#pragma unroll
        for (int mf = 0; mf < 4; ++mf)
#pragma unroll
            for (int nf = 0; nf < 2; ++nf) {
                acc[mf + 4][nf] = __builtin_amdgcn_mfma_f32_16x16x32_bf16(a[mf][0], bl[nf][0], acc[mf + 4][nf], 0, 0, 0);
                acc[mf + 4][nf] = __builtin_amdgcn_mfma_f32_16x16x32_bf16(a[mf][1], bl[nf][1], acc[mf + 4][nf], 0, 0, 0);
            }
        __builtin_amdgcn_s_setprio(0);
        __builtin_amdgcn_s_barrier();
        asm volatile("" ::: "memory");
    }

#pragma unroll
    for (int mf = 0; mf < 8; ++mf)
#pragma unroll
        for (int nf = 0; nf < 4; ++nf)
#pragma unroll
            for (int r = 0; r < 4; ++r) {
                int row = bm + wm * 128 + mf * 16 + quad * 4 + r;
                int col = bn + wn * 64 + nf * 16 + l16;
                C[(size_t)row * ldc + col] = f2bf(acc[mf][nf][r]);
            }
}

// ---------------- phase-split GEMM (R4-proven p4 schedule, BN templated) -----------
template <int BN, typename OutT>
__global__ __launch_bounds__(512, 1) void gemm_p4(const u16* __restrict__ A,
                                                  const u16* __restrict__ B,
                                                  OutT* __restrict__ C,
                                                  int K, int ldc) {
    constexpr int BM = 256;
    constexpr int NF = BN / 32;
    constexpr int LB = BN / 64;
    constexpr int VW = 4 + LB;
    __shared__ __align__(16) u16 As[2][BM * 64];
    __shared__ __align__(16) u16 Bs[2][BN * 64];
    const int tid = threadIdx.x;
    const int wid = tid >> 6, lane = tid & 63;
    const int quad = lane >> 4, l16 = lane & 15;
    const int wm = wid >> 1, wn = wid & 1;
    const int bm = blockIdx.x * BM, bn = blockIdx.y * BN;
    const int NT = K >> 6;

    const u16* aSrc[4];
    const u16* bSrc[LB];
#pragma unroll
    for (int j = 0; j < 4; ++j) {
        int c = j * 512 + tid, row = c >> 3, ch = c & 7;
        aSrc[j] = A + (size_t)(bm + row) * K + (ch ^ (row & 7)) * 8;
    }
#pragma unroll
    for (int j = 0; j < LB; ++j) {
        int c = j * 512 + tid, row = c >> 3, ch = c & 7;
        bSrc[j] = B + (size_t)(bn + row) * K + (ch ^ (row & 7)) * 8;
    }

    const int swz = l16 & 7;
    const int aBase = (wm * 64 + l16) * 64;
    const int bBase = (wn * (BN / 2) + l16) * 64;
    const int c0 = (quad ^ swz) * 8;
    const int c1 = ((4 | quad) ^ swz) * 8;

    f32x4 acc[4][NF] = {};

#pragma unroll
    for (int j = 0; j < 4; ++j) gl_lds16(aSrc[j], &As[0][(j * 512 + tid) * 8]);
#pragma unroll
    for (int j = 0; j < LB; ++j) gl_lds16(bSrc[j], &Bs[0][(j * 512 + tid) * 8]);
#pragma unroll
    for (int j = 0; j < 4; ++j) gl_lds16(aSrc[j] + 64, &As[1][(j * 512 + tid) * 8]);
#pragma unroll
    for (int j = 0; j < LB; ++j) gl_lds16(bSrc[j] + 64, &Bs[1][(j * 512 + tid) * 8]);
    waitcnt_vm<VW>();
    __builtin_amdgcn_s_barrier();
    asm volatile("" ::: "memory");

    int koff = 128;
    for (int t = 0; t < NT; ++t) {
        const u16* ab = &As[t & 1][0];
        const u16* bb = &Bs[t & 1][0];

        bfrag a0[4], b0[NF], a1[4], b1[NF];
#pragma unroll
        for (int mf = 0; mf < 4; ++mf) a0[mf] = *(const bfrag*)&ab[aBase + mf * 1024 + c0];
#pragma unroll
        for (int nf = 0; nf < NF; ++nf) b0[nf] = *(const bfrag*)&bb[bBase + nf * 1024 + c0];
#pragma unroll
        for (int mf = 0; mf < 4; ++mf) a1[mf] = *(const bfrag*)&ab[aBase + mf * 1024 + c1];
#pragma unroll
        for (int nf = 0; nf < NF; ++nf) b1[nf] = *(const bfrag*)&bb[bBase + nf * 1024 + c1];

        __builtin_amdgcn_s_setprio(1);
#pragma unroll
        for (int mf = 0; mf < 4; ++mf)
#pragma unroll
            for (int nf = 0; nf < NF; ++nf)
                acc[mf][nf] = __builtin_amdgcn_mfma_f32_16x16x32_bf16(a0[mf], b0[nf], acc[mf][nf], 0, 0, 0);
        __builtin_amdgcn_s_setprio(0);

        asm volatile("s_waitcnt lgkmcnt(0)" ::: "memory");
        __builtin_amdgcn_s_barrier();
        asm volatile("" ::: "memory");

        if (t + 2 < NT) {
#pragma unroll
            for (int j = 0; j < 4; ++j) gl_lds16(aSrc[j] + koff, &As[t & 1][(j * 512 + tid) * 8]);
#pragma unroll
            for (int j = 0; j < LB; ++j) gl_lds16(bSrc[j] + koff, &Bs[t & 1][(j * 512 + tid) * 8]);
            koff += 64;
        }

        __builtin_amdgcn_s_setprio(1);
#pragma unroll
        for (int mf = 0; mf < 4; ++mf)
#pragma unroll
            for (int nf = 0; nf < NF; ++nf)
                acc[mf][nf] = __builtin_amdgcn_mfma_f32_16x16x32_bf16(a1[mf], b1[nf], acc[mf][nf], 0, 0, 0);
        __builtin_amdgcn_s_setprio(0);

        if (t + 2 < NT)      waitcnt_vm<VW>();
        else if (t + 1 < NT) waitcnt_vm<0>();
        if (t + 1 < NT) {
            __builtin_amdgcn_s_barrier();
            asm volatile("" ::: "memory");
        }
    }

#pragma unroll
    for (int mf = 0; mf < 4; ++mf)
#pragma unroll
        for (int nf = 0; nf < NF; ++nf)
#pragma unroll
            for (int r = 0; r < 4; ++r) {
                int row = bm + wm * 64 + mf * 16 + quad * 4 + r;
                int col = bn + wn * (BN / 2) + nf * 16 + l16;
                float v = acc[mf][nf][r];
                if constexpr (sizeof(OutT) == 2)
                    C[(size_t)row * ldc + col] = f2bf(v);
                else
                    C[(size_t)row * ldc + col] = v;
            }
}

// ---------------- RMSNorm + RoPE (q prescaled by softmax scale * log2e) ----------------
__global__ __launch_bounds__(256) void rmsrope(u16* __restrict__ qkv,
                                               const float* __restrict__ cosb,
                                               const float* __restrict__ sinb,
                                               const float* __restrict__ qw,
                                               const float* __restrict__ kw) {
    const float c1 = 0.08838834764831845f * LOG2E;
    int wave = threadIdx.x >> 6, lane = threadIdx.x & 63;
    int pi = blockIdx.x * 4 + wave;
    int m = pi / 20, hsel = pi % 20;
    int col0 = hsel < 16 ? hsel * 128 : 2048 + (hsel - 16) * 128;
    const float* w = hsel < 16 ? qw : kw;
    float sc = hsel < 16 ? c1 : 1.0f;
    int s = m & 2047;
    u16* p = qkv + (size_t)m * 3072 + col0;
    float x1 = bf2f(p[lane]), x2 = bf2f(p[lane + 64]);
    float ss = x1 * x1 + x2 * x2;
#pragma unroll
    for (int off = 32; off; off >>= 1) ss += __shfl_xor(ss, off, 64);
    float inv = rsqrtf(ss * (1.0f / 128.0f) + 1e-6f);
    float y1 = x1 * inv * w[lane], y2 = x2 * inv * w[lane + 64];
    const float* cp = cosb + (size_t)s * 128;
    const float* sp = sinb + (size_t)s * 128;
    float o1 = y1 * cp[lane] - y2 * sp[lane];
    float o2 = y2 * cp[lane + 64] + y1 * sp[lane + 64];
    p[lane] = f2bf(o1 * sc);
    p[lane + 64] = f2bf(o2 * sc);
}

// ---------------- V transpose ----------------
__global__ __launch_bounds__(256) void transpose_v(const u16* __restrict__ qkv,
                                                   u16* __restrict__ vT) {
    __shared__ u16 t[32][33];
    int bh = blockIdx.z, b = bh >> 2, kvh = bh & 3;
    int s0 = blockIdx.y * 32, d0 = blockIdx.x * 32;
    int tx = threadIdx.x, ty = threadIdx.y;
    const u16* src = qkv + (size_t)(b * 2048) * 3072 + 2560 + kvh * 128;
#pragma unroll
    for (int i = 0; i < 32; i += 8)
        t[ty + i][tx] = src[(size_t)(s0 + ty + i) * 3072 + d0 + tx];
    __syncthreads();
    u16* dst = vT + (size_t)bh * 128 * 2048;
#pragma unroll
    for (int i = 0; i < 32; i += 8)
        dst[(size_t)(d0 + ty + i) * 2048 + s0 + tx] = t[tx][ty + i];
}

// ---------------- causal flash attention v5 (exact R9 revert: best measured 65.6us) --
__global__ __launch_bounds__(512, 4) void attn_kernel(const u16* __restrict__ qkv,
                                                      const u16* __restrict__ vT,
                                                      u16* __restrict__ out) {
    __shared__ u16 Ks[2][64 * 128];    // [buf][row-pos][16B-chunk ^ (pos&15)] (rows PERMUTED)
    __shared__ u16 VsT[2][128 * 64];   // [buf][d][16B-chunk ^ (d&7)] (natural kv order)
    const int tid = threadIdx.x, wave = tid >> 6, lane = tid & 63;
    const int quad = lane >> 4, l16 = lane & 15;
    const int ws = wave & 3;           // row-group within my tile
    const int bh = blockIdx.x, b = bh >> 4, h = bh & 15, kvh = h >> 2;
    const int pair = blockIdx.y;
    const int qtA = pair, qtB = 31 - pair;
    const int myQt = (wave < 4) ? qtA : qtB;   // wave-uniform
    const int NT = qtB + 1;
    const size_t rowBase = (size_t)b * 2048;
    const int kcol0 = 2048 + kvh * 128;
    const u16* vTbase = vT + (size_t)(b * 4 + kvh) * 128 * 2048;

    const int qrow = myQt * 64 + ws * 16 + l16;  // this lane's q row

    // Q B-frags (K=32): lane l16 holds d = ks*32 + quad*8 + j
    bfrag qf[4];
    {
        const u16* qp = qkv + (rowBase + qrow) * 3072 + h * 128 + quad * 8;
#pragma unroll
        for (int ks = 0; ks < 4; ++ks) qf[ks] = *(const bfrag*)(qp + ks * 32);
    }
    asm volatile("s_waitcnt vmcnt(0)" ::: "memory");
#pragma unroll
    for (int ks = 0; ks < 4; ++ks) {
        uint4 t = __builtin_bit_cast(uint4, qf[ks]);
        asm volatile("" : "+v"(t.x), "+v"(t.y), "+v"(t.z), "+v"(t.w));
        qf[ks] = __builtin_bit_cast(bfrag, t);
    }

    // persistent stage pointers (pre-swizzled), 512 threads: 2 K + 2 V loads each.
    // K source row = PERMUTED: pos x -> kv 32*(m>>1) + 8*q + 4*(m&1) + r.
    const u16* kp[2];
    const u16* vp[2];
#pragma unroll
    for (int i = 0; i < 2; ++i) {  // Ks: 64 rows x 16 chunks = 1024
        int c = i * 512 + tid, pos = c >> 4, cp2 = c & 15;
        int m = pos >> 4, qd = (pos >> 2) & 3, r = pos & 3;
        int kvp = 32 * (m >> 1) + 8 * qd + 4 * (m & 1) + r;
        kp[i] = qkv + (rowBase + kvp) * 3072 + kcol0 + (cp2 ^ (pos & 15)) * 8;
    }
#pragma unroll
    for (int i = 0; i < 2; ++i) {  // VsT: 128 rows x 8 chunks = 1024
        int c = i * 512 + tid, d = c >> 3, cp2 = c & 7;
        vp[i] = vTbase + (size_t)d * 2048 + (cp2 ^ (d & 7)) * 8;
    }

    f32x4 o[8] = {};
    float lrun = 0.f;

    // stage tile 0 -> buf 0; advance ptrs to tile 1
#pragma unroll
    for (int i = 0; i < 2; ++i) gl_lds16(kp[i], &Ks[0][(i * 512 + tid) * 8]);
#pragma unroll
    for (int i = 0; i < 2; ++i) gl_lds16(vp[i], &VsT[0][(i * 512 + tid) * 8]);
#pragma unroll
    for (int i = 0; i < 2; ++i) { kp[i] += 64 * 3072; vp[i] += 64; }

#pragma unroll 1
    for (int kt = 0; kt < NT; ++kt) {
        const int cur = kt & 1;
        if (kt + 1 < NT) {
#pragma unroll
            for (int i = 0; i < 2; ++i) gl_lds16(kp[i], &Ks[cur ^ 1][(i * 512 + tid) * 8]);
#pragma unroll
            for (int i = 0; i < 2; ++i) gl_lds16(vp[i], &VsT[cur ^ 1][(i * 512 + tid) * 8]);
#pragma unroll
            for (int i = 0; i < 2; ++i) { kp[i] += 64 * 3072; vp[i] += 64; }
            waitcnt_vm<4>();
        } else {
            waitcnt_vm<0>();
        }
        __builtin_amdgcn_s_barrier();
        asm volatile("" ::: "memory");

        if (kt <= myQt) {  // wave-uniform
            const int kv0 = kt * 64;

            // S^T = K * Q^T (rows permuted; scores in exp2-domain)
            f32x4 sa[4] = {};
            __builtin_amdgcn_s_setprio(1);
#pragma unroll
            for (int ks = 0; ks < 4; ++ks)
#pragma unroll
                for (int m = 0; m < 4; ++m) {
                    bfrag kf = *(const bfrag*)&Ks[cur][((m * 16 + l16) * 16 + ((ks * 4 + quad) ^ l16)) * 8];
                    sa[m] = __builtin_amdgcn_mfma_f32_16x16x32_bf16(kf, qf[ks], sa[m], 0, 0, 0);
                }
            __builtin_amdgcn_s_setprio(0);

            // no-max softmax; masked -> -3e38 underflows to 0 in exp2.
            // sa[m][r] at lane quad holds kv = kv0 + 32*(m>>1) + 8*quad + 4*(m&1) + r.
            if (kv0 + 63 > myQt * 64 + ws * 16) {  // diagonal tile only
#pragma unroll
                for (int m = 0; m < 4; ++m)
#pragma unroll
                    for (int r = 0; r < 4; ++r)
                        if (kv0 + 32 * (m >> 1) + 8 * quad + 4 * (m & 1) + r > qrow)
                            sa[m][r] = -3e38f;
            }
            float rs = 0.f;
#pragma unroll
            for (int m = 0; m < 4; ++m)
#pragma unroll
                for (int r = 0; r < 4; ++r) {
                    float pe = exp2f(sa[m][r]);
                    sa[m][r] = pe;
                    rs += pe;
                }
            rs += __shfl_xor(rs, 16, 64);
            rs += __shfl_xor(rs, 32, 64);
            lrun += rs;

            // P -> bf16; pk[2ks2],pk[2ks2+1] form the K=32 B-frag directly
            uint2 pk[4];
#pragma unroll
            for (int m = 0; m < 4; ++m) pk[m] = pack4(sa[m]);
            bfrag pb[2];
            pb[0] = __builtin_bit_cast(bfrag, (uint4){pk[0].x, pk[0].y, pk[1].x, pk[1].y});
            pb[1] = __builtin_bit_cast(bfrag, (uint4){pk[2].x, pk[2].y, pk[3].x, pk[3].y});

            // O^T += V^T * P^T : K=32 MFMA, A = V^T b128 (gemm-proven conflict-free)
            __builtin_amdgcn_s_setprio(1);
#pragma unroll
            for (int ks2 = 0; ks2 < 2; ++ks2) {
#pragma unroll
                for (int dt = 0; dt < 8; ++dt) {
                    int d = dt * 16 + l16;
                    bfrag vf = *(const bfrag*)&VsT[cur][(d * 8 + ((ks2 * 4 + quad) ^ (d & 7))) * 8];
                    o[dt] = __builtin_amdgcn_mfma_f32_16x16x32_bf16(vf, pb[ks2], o[dt], 0, 0, 0);
                }
            }
            __builtin_amdgcn_s_setprio(0);
        }
        asm volatile("" ::: "memory");
        __builtin_amdgcn_s_barrier();  // all reads of buf[cur] done before overwrite
    }

    // epilogue: normalize, pack, store 8B per (lane, dtile)
    float inv = 1.0f / lrun;
    size_t orow = (rowBase + qrow) * 2048 + h * 128 + quad * 4;
#pragma unroll
    for (int dt = 0; dt < 8; ++dt) {
        float a0 = o[dt][0] * inv, a1 = o[dt][1] * inv;
        float a2 = o[dt][2] * inv, a3 = o[dt][3] * inv;
        uint2 pko;
        asm("v_cvt_pk_bf16_f32 %0, %1, %2" : "=v"(pko.x) : "v"(a0), "v"(a1));
        asm("v_cvt_pk_bf16_f32 %0, %1, %2" : "=v"(pko.y) : "v"(a2), "v"(a3));
        *(uint2*)(out + orow + dt * 16) = pko;
    }
}

extern "C" void kernel_launch(void* const* d_in, const int* in_sizes, int n_in,
                              void* d_out, int out_size, void* d_ws, size_t ws_size,
                              hipStream_t stream) {
    const float* hs   = (const float*)d_in[0];
    const float* cosb = (const float*)d_in[1];
    const float* sinb = (const float*)d_in[2];
    const float* Wq = (const float*)d_in[4];
    const float* Wk = (const float*)d_in[5];
    const float* Wv = (const float*)d_in[6];
    const float* Wo = (const float*)d_in[7];
    const float* qw = (const float*)d_in[8];
    const float* kw = (const float*)d_in[9];
    float* out = (float*)d_out;

    char* ws = (char*)d_ws;
    u16* hsb   = (u16*)(ws + 0);          // 16 MB: hs bf16; later reused as attn-out bf16
    u16* wqkvT = (u16*)(ws + 16777216);   // 12 MB
    u16* woT   = (u16*)(ws + 29360128);   // 8 MB
    u16* qkv   = (u16*)(ws + 37748736);   // 24 MB
    u16* vT    = (u16*)(ws + 62914560);   // 4 MB

    dim3 tb(32, 8);
    cvt_f32_bf16<<<8192, 256, 0, stream>>>(hs, hsb, 2097152);
    transpose_cvt<<<dim3(64, 64), tb, 0, stream>>>(Wq, wqkvT, 2048, 2048);
    transpose_cvt<<<dim3(16, 64), tb, 0, stream>>>(Wk, wqkvT + (size_t)2048 * 2048, 2048, 512);
    transpose_cvt<<<dim3(16, 64), tb, 0, stream>>>(Wv, wqkvT + (size_t)2560 * 2048, 2048, 512);
    transpose_cvt<<<dim3(64, 64), tb, 0, stream>>>(Wo, woT, 2048, 2048);

    // QKV projection: M=4096, N=3072, K=2048 -> 8-phase 256x256: 16x12 = 192 blocks
    gemm8<<<dim3(16, 12), 512, 0, stream>>>(hsb, wqkvT, qkv, 2048, 3072);

    rmsrope<<<20480, 256, 0, stream>>>(qkv, cosb, sinb, qw, kw);
    transpose_v<<<dim3(4, 64, 8), tb, 0, stream>>>(qkv, vT);

    attn_kernel<<<dim3(32, 16), 512, 0, stream>>>(qkv, vT, hsb);

    // O projection: M=4096, N=2048, K=2048 -> BN=128: 16x16 = 256 blocks
    gemm_p4<128, float><<<dim3(16, 16), 512, 0, stream>>>(hsb, woT, out, 2048, 2048);
}

// Round 12
// 307.298 us; speedup vs baseline: 1.0459x; 1.0459x over previous
//
#include <hip/hip_runtime.h>
#include <stdint.h>

typedef unsigned short u16;
typedef __bf16 bfrag __attribute__((ext_vector_type(8)));   // 8 bf16 = 4 VGPRs (MFMA A/B, K=32)
typedef float f32x4 __attribute__((ext_vector_type(4)));    // MFMA C/D

#define LOG2E 1.44269504088896340736f

__device__ __forceinline__ u16 f2bf(float f) {
    unsigned u = __builtin_bit_cast(unsigned, f);
    u = (u + 0x7fffu + ((u >> 16) & 1u)) >> 16;
    return (u16)u;
}
__device__ __forceinline__ float bf2f(u16 x) {
    unsigned u = ((unsigned)x) << 16;
    return __builtin_bit_cast(float, u);
}

__device__ __forceinline__ void gl_lds16(const u16* g, u16* l) {
#if __has_builtin(__builtin_amdgcn_global_load_lds)
    __builtin_amdgcn_global_load_lds(
        (const __attribute__((address_space(1))) unsigned int*)g,
        (__attribute__((address_space(3))) unsigned int*)l, 16, 0, 0);
#else
    *(uint4*)l = *(const uint4*)g;
#endif
}

template <int N>
__device__ __forceinline__ void waitcnt_vm() {
    if constexpr (N == 0)      asm volatile("s_waitcnt vmcnt(0)" ::: "memory");
    else if constexpr (N == 4) asm volatile("s_waitcnt vmcnt(4)" ::: "memory");
    else if constexpr (N == 5) asm volatile("s_waitcnt vmcnt(5)" ::: "memory");
    else if constexpr (N == 6) asm volatile("s_waitcnt vmcnt(6)" ::: "memory");
    else if constexpr (N == 7) asm volatile("s_waitcnt vmcnt(7)" ::: "memory");
    else if constexpr (N == 8) asm volatile("s_waitcnt vmcnt(8)" ::: "memory");
}

// pack 4 f32 -> 2x u32 of bf16 pairs via v_cvt_pk_bf16_f32 (RNE)
__device__ __forceinline__ uint2 pack4(const f32x4& v) {
    uint2 u;
    asm("v_cvt_pk_bf16_f32 %0, %1, %2" : "=v"(u.x) : "v"(v[0]), "v"(v[1]));
    asm("v_cvt_pk_bf16_f32 %0, %1, %2" : "=v"(u.y) : "v"(v[2]), "v"(v[3]));
    return u;
}

// ---------------- fp32 -> bf16 elementwise ----------------
__global__ __launch_bounds__(256) void cvt_f32_bf16(const float* __restrict__ s,
                                                    u16* __restrict__ d, int n4) {
    int i = blockIdx.x * 256 + threadIdx.x;
    if (i < n4) {
        float4 v = ((const float4*)s)[i];
        uint2 o;
        o.x = (unsigned)f2bf(v.x) | ((unsigned)f2bf(v.y) << 16);
        o.y = (unsigned)f2bf(v.z) | ((unsigned)f2bf(v.w) << 16);
        ((uint2*)d)[i] = o;
    }
}

// ---------------- transpose + convert ----------------
__global__ __launch_bounds__(256) void transpose_cvt(const float* __restrict__ src,
                                                     u16* __restrict__ dst,
                                                     int rows, int cols) {
    __shared__ float tile[32][33];
    int c0 = blockIdx.x * 32, r0 = blockIdx.y * 32;
    int tx = threadIdx.x, ty = threadIdx.y;
#pragma unroll
    for (int i = 0; i < 32; i += 8)
        tile[ty + i][tx] = src[(size_t)(r0 + ty + i) * cols + c0 + tx];
    __syncthreads();
#pragma unroll
    for (int i = 0; i < 32; i += 8)
        dst[(size_t)(c0 + ty + i) * rows + r0 + tx] = f2bf(tile[tx][ty + i]);
}

// ---------------- phase-split GEMM (R4-proven p4 schedule, BN templated) -----------
// R9-best config: QKV BN=192 (grid 16x16 = 256 blocks, no tail), O-proj BN=128.
// R11 lesson: the 8-phase 256x256 variant is +18% per-CU but its 192-block grid
// idles 64 CUs -> net -13us. Grid-filling beats schedule depth at these shapes.
template <int BN, typename OutT>
__global__ __launch_bounds__(512, 1) void gemm_p4(const u16* __restrict__ A,
                                                  const u16* __restrict__ B,
                                                  OutT* __restrict__ C,
                                                  int K, int ldc) {
    constexpr int BM = 256;
    constexpr int NF = BN / 32;
    constexpr int LB = BN / 64;
    constexpr int VW = 4 + LB;
    __shared__ __align__(16) u16 As[2][BM * 64];
    __shared__ __align__(16) u16 Bs[2][BN * 64];
    const int tid = threadIdx.x;
    const int wid = tid >> 6, lane = tid & 63;
    const int quad = lane >> 4, l16 = lane & 15;
    const int wm = wid >> 1, wn = wid & 1;
    const int bm = blockIdx.x * BM, bn = blockIdx.y * BN;
    const int NT = K >> 6;

    const u16* aSrc[4];
    const u16* bSrc[LB];
#pragma unroll
    for (int j = 0; j < 4; ++j) {
        int c = j * 512 + tid, row = c >> 3, ch = c & 7;
        aSrc[j] = A + (size_t)(bm + row) * K + (ch ^ (row & 7)) * 8;
    }
#pragma unroll
    for (int j = 0; j < LB; ++j) {
        int c = j * 512 + tid, row = c >> 3, ch = c & 7;
        bSrc[j] = B + (size_t)(bn + row) * K + (ch ^ (row & 7)) * 8;
    }

    const int swz = l16 & 7;
    const int aBase = (wm * 64 + l16) * 64;
    const int bBase = (wn * (BN / 2) + l16) * 64;
    const int c0 = (quad ^ swz) * 8;
    const int c1 = ((4 | quad) ^ swz) * 8;

    f32x4 acc[4][NF] = {};

#pragma unroll
    for (int j = 0; j < 4; ++j) gl_lds16(aSrc[j], &As[0][(j * 512 + tid) * 8]);
#pragma unroll
    for (int j = 0; j < LB; ++j) gl_lds16(bSrc[j], &Bs[0][(j * 512 + tid) * 8]);
#pragma unroll
    for (int j = 0; j < 4; ++j) gl_lds16(aSrc[j] + 64, &As[1][(j * 512 + tid) * 8]);
#pragma unroll
    for (int j = 0; j < LB; ++j) gl_lds16(bSrc[j] + 64, &Bs[1][(j * 512 + tid) * 8]);
    waitcnt_vm<VW>();
    __builtin_amdgcn_s_barrier();
    asm volatile("" ::: "memory");

    int koff = 128;
    for (int t = 0; t < NT; ++t) {
        const u16* ab = &As[t & 1][0];
        const u16* bb = &Bs[t & 1][0];

        bfrag a0[4], b0[NF], a1[4], b1[NF];
#pragma unroll
        for (int mf = 0; mf < 4; ++mf) a0[mf] = *(const bfrag*)&ab[aBase + mf * 1024 + c0];
#pragma unroll
        for (int nf = 0; nf < NF; ++nf) b0[nf] = *(const bfrag*)&bb[bBase + nf * 1024 + c0];
#pragma unroll
        for (int mf = 0; mf < 4; ++mf) a1[mf] = *(const bfrag*)&ab[aBase + mf * 1024 + c1];
#pragma unroll
        for (int nf = 0; nf < NF; ++nf) b1[nf] = *(const bfrag*)&bb[bBase + nf * 1024 + c1];

        __builtin_amdgcn_s_setprio(1);
#pragma unroll
        for (int mf = 0; mf < 4; ++mf)
#pragma unroll
            for (int nf = 0; nf < NF; ++nf)
                acc[mf][nf] = __builtin_amdgcn_mfma_f32_16x16x32_bf16(a0[mf], b0[nf], acc[mf][nf], 0, 0, 0);
        __builtin_amdgcn_s_setprio(0);

        asm volatile("s_waitcnt lgkmcnt(0)" ::: "memory");
        __builtin_amdgcn_s_barrier();
        asm volatile("" ::: "memory");

        if (t + 2 < NT) {
#pragma unroll
            for (int j = 0; j < 4; ++j) gl_lds16(aSrc[j] + koff, &As[t & 1][(j * 512 + tid) * 8]);
#pragma unroll
            for (int j = 0; j < LB; ++j) gl_lds16(bSrc[j] + koff, &Bs[t & 1][(j * 512 + tid) * 8]);
            koff += 64;
        }

        __builtin_amdgcn_s_setprio(1);
#pragma unroll
        for (int mf = 0; mf < 4; ++mf)
#pragma unroll
            for (int nf = 0; nf < NF; ++nf)
                acc[mf][nf] = __builtin_amdgcn_mfma_f32_16x16x32_bf16(a1[mf], b1[nf], acc[mf][nf], 0, 0, 0);
        __builtin_amdgcn_s_setprio(0);

        if (t + 2 < NT)      waitcnt_vm<VW>();
        else if (t + 1 < NT) waitcnt_vm<0>();
        if (t + 1 < NT) {
            __builtin_amdgcn_s_barrier();
            asm volatile("" ::: "memory");
        }
    }

#pragma unroll
    for (int mf = 0; mf < 4; ++mf)
#pragma unroll
        for (int nf = 0; nf < NF; ++nf)
#pragma unroll
            for (int r = 0; r < 4; ++r) {
                int row = bm + wm * 64 + mf * 16 + quad * 4 + r;
                int col = bn + wn * (BN / 2) + nf * 16 + l16;
                float v = acc[mf][nf][r];
                if constexpr (sizeof(OutT) == 2)
                    C[(size_t)row * ldc + col] = f2bf(v);
                else
                    C[(size_t)row * ldc + col] = v;
            }
}

// ---------------- RMSNorm + RoPE (q prescaled by softmax scale * log2e) ----------------
__global__ __launch_bounds__(256) void rmsrope(u16* __restrict__ qkv,
                                               const float* __restrict__ cosb,
                                               const float* __restrict__ sinb,
                                               const float* __restrict__ qw,
                                               const float* __restrict__ kw) {
    const float c1 = 0.08838834764831845f * LOG2E;
    int wave = threadIdx.x >> 6, lane = threadIdx.x & 63;
    int pi = blockIdx.x * 4 + wave;
    int m = pi / 20, hsel = pi % 20;
    int col0 = hsel < 16 ? hsel * 128 : 2048 + (hsel - 16) * 128;
    const float* w = hsel < 16 ? qw : kw;
    float sc = hsel < 16 ? c1 : 1.0f;
    int s = m & 2047;
    u16* p = qkv + (size_t)m * 3072 + col0;
    float x1 = bf2f(p[lane]), x2 = bf2f(p[lane + 64]);
    float ss = x1 * x1 + x2 * x2;
#pragma unroll
    for (int off = 32; off; off >>= 1) ss += __shfl_xor(ss, off, 64);
    float inv = rsqrtf(ss * (1.0f / 128.0f) + 1e-6f);
    float y1 = x1 * inv * w[lane], y2 = x2 * inv * w[lane + 64];
    const float* cp = cosb + (size_t)s * 128;
    const float* sp = sinb + (size_t)s * 128;
    float o1 = y1 * cp[lane] - y2 * sp[lane];
    float o2 = y2 * cp[lane + 64] + y1 * sp[lane + 64];
    p[lane] = f2bf(o1 * sc);
    p[lane + 64] = f2bf(o2 * sc);
}

// ---------------- V transpose ----------------
__global__ __launch_bounds__(256) void transpose_v(const u16* __restrict__ qkv,
                                                   u16* __restrict__ vT) {
    __shared__ u16 t[32][33];
    int bh = blockIdx.z, b = bh >> 2, kvh = bh & 3;
    int s0 = blockIdx.y * 32, d0 = blockIdx.x * 32;
    int tx = threadIdx.x, ty = threadIdx.y;
    const u16* src = qkv + (size_t)(b * 2048) * 3072 + 2560 + kvh * 128;
#pragma unroll
    for (int i = 0; i < 32; i += 8)
        t[ty + i][tx] = src[(size_t)(s0 + ty + i) * 3072 + d0 + tx];
    __syncthreads();
    u16* dst = vT + (size_t)bh * 128 * 2048;
#pragma unroll
    for (int i = 0; i < 32; i += 8)
        dst[(size_t)(d0 + ty + i) * 2048 + s0 + tx] = t[tx][ty + i];
}

// ---------------- causal flash attention v7 = v5 + single-barrier + balanced pairs ---
// v5 (R9-proven, 65.6us): K-row perm -> K=32 PV, 0 bank conflicts, 8-wave split-tile.
// v7 deltas (both derived, low-risk):
//  - SINGLE barrier/iter: stage is issued AFTER the barrier. Safety: a wave reaches
//    iteration kt's barrier only after finishing kt-1's compute, so when any wave
//    stages tile kt+1 into buf[cur^1] (post-barrier), ALL waves have finished
//    reading buf[cur^1] (their kt-1 compute). vmcnt(0) at top waits only tile kt's
//    4 loads, which had a full compute phase (>> ~900cy HBM latency) to land.
//  - balanced pair remap: block wall ~ NT = 32-pair. Under round-robin dispatch,
//    blocks n and n+256 co-reside (same XCD/CU) -> remap pair = y<8 ? y : 23-y
//    makes co-resident NT sums constant (49) for every CU (was 42..56, 14% spread).
//    Speed-only heuristic: bijective on 0..15, correctness mapping-independent.
__global__ __launch_bounds__(512, 4) void attn_kernel(const u16* __restrict__ qkv,
                                                      const u16* __restrict__ vT,
                                                      u16* __restrict__ out) {
    __shared__ u16 Ks[2][64 * 128];    // [buf][row-pos][16B-chunk ^ (pos&15)] (rows PERMUTED)
    __shared__ u16 VsT[2][128 * 64];   // [buf][d][16B-chunk ^ (d&7)] (natural kv order)
    const int tid = threadIdx.x, wave = tid >> 6, lane = tid & 63;
    const int quad = lane >> 4, l16 = lane & 15;
    const int ws = wave & 3;           // row-group within my tile
    const int bh = blockIdx.x, b = bh >> 4, h = bh & 15, kvh = h >> 2;
    const int y = blockIdx.y;
    const int pair = (y < 8) ? y : 23 - y;     // balanced remap (bijective 0..15)
    const int qtA = pair, qtB = 31 - pair;
    const int myQt = (wave < 4) ? qtA : qtB;   // wave-uniform
    const int NT = qtB + 1;
    const size_t rowBase = (size_t)b * 2048;
    const int kcol0 = 2048 + kvh * 128;
    const u16* vTbase = vT + (size_t)(b * 4 + kvh) * 128 * 2048;

    const int qrow = myQt * 64 + ws * 16 + l16;  // this lane's q row

    // Q B-frags (K=32): lane l16 holds d = ks*32 + quad*8 + j
    bfrag qf[4];
    {
        const u16* qp = qkv + (rowBase + qrow) * 3072 + h * 128 + quad * 8;
#pragma unroll
        for (int ks = 0; ks < 4; ++ks) qf[ks] = *(const bfrag*)(qp + ks * 32);
    }
    asm volatile("s_waitcnt vmcnt(0)" ::: "memory");
#pragma unroll
    for (int ks = 0; ks < 4; ++ks) {
        uint4 t = __builtin_bit_cast(uint4, qf[ks]);
        asm volatile("" : "+v"(t.x), "+v"(t.y), "+v"(t.z), "+v"(t.w));
        qf[ks] = __builtin_bit_cast(bfrag, t);
    }

    // persistent stage pointers (pre-swizzled), 512 threads: 2 K + 2 V loads each.
    // K source row = PERMUTED: pos x -> kv 32*(m>>1) + 8*q + 4*(m&1) + r.
    const u16* kp[2];
    const u16* vp[2];
#pragma unroll
    for (int i = 0; i < 2; ++i) {  // Ks: 64 rows x 16 chunks = 1024
        int c = i * 512 + tid, pos = c >> 4, cp2 = c & 15;
        int m = pos >> 4, qd = (pos >> 2) & 3, r = pos & 3;
        int kvp = 32 * (m >> 1) + 8 * qd + 4 * (m & 1) + r;
        kp[i] = qkv + (rowBase + kvp) * 3072 + kcol0 + (cp2 ^ (pos & 15)) * 8;
    }
#pragma unroll
    for (int i = 0; i < 2; ++i) {  // VsT: 128 rows x 8 chunks = 1024
        int c = i * 512 + tid, d = c >> 3, cp2 = c & 7;
        vp[i] = vTbase + (size_t)d * 2048 + (cp2 ^ (d & 7)) * 8;
    }

    f32x4 o[8] = {};
    float lrun = 0.f;

    // stage tile 0 -> buf 0; advance ptrs to tile 1
#pragma unroll
    for (int i = 0; i < 2; ++i) gl_lds16(kp[i], &Ks[0][(i * 512 + tid) * 8]);
#pragma unroll
    for (int i = 0; i < 2; ++i) gl_lds16(vp[i], &VsT[0][(i * 512 + tid) * 8]);
#pragma unroll
    for (int i = 0; i < 2; ++i) { kp[i] += 64 * 3072; vp[i] += 64; }

#pragma unroll 1
    for (int kt = 0; kt < NT; ++kt) {
        const int cur = kt & 1;
        // tile kt resident (own DMAs retired) -> barrier: all waves' DMAs landed AND
        // all waves finished kt-1's compute (so buf[cur^1] is now write-safe).
        waitcnt_vm<0>();
        __builtin_amdgcn_s_barrier();
        asm volatile("" ::: "memory");

        if (kt + 1 < NT) {  // stage tile kt+1 into buf[cur^1] (post-barrier: race-free)
#pragma unroll
            for (int i = 0; i < 2; ++i) gl_lds16(kp[i], &Ks[cur ^ 1][(i * 512 + tid) * 8]);
#pragma unroll
            for (int i = 0; i < 2; ++i) gl_lds16(vp[i], &VsT[cur ^ 1][(i * 512 + tid) * 8]);
#pragma unroll
            for (int i = 0; i < 2; ++i) { kp[i] += 64 * 3072; vp[i] += 64; }
        }

        if (kt <= myQt) {  // wave-uniform
            const int kv0 = kt * 64;

            // S^T = K * Q^T (rows permuted; scores in exp2-domain)
            f32x4 sa[4] = {};
            __builtin_amdgcn_s_setprio(1);
#pragma unroll
            for (int ks = 0; ks < 4; ++ks)
#pragma unroll
                for (int m = 0; m < 4; ++m) {
                    bfrag kf = *(const bfrag*)&Ks[cur][((m * 16 + l16) * 16 + ((ks * 4 + quad) ^ l16)) * 8];
                    sa[m] = __builtin_amdgcn_mfma_f32_16x16x32_bf16(kf, qf[ks], sa[m], 0, 0, 0);
                }
            __builtin_amdgcn_s_setprio(0);

            // no-max softmax; masked -> -3e38 underflows to 0 in exp2.
            // sa[m][r] at lane quad holds kv = kv0 + 32*(m>>1) + 8*quad + 4*(m&1) + r.
            if (kv0 + 63 > myQt * 64 + ws * 16) {  // diagonal tile only
#pragma unroll
                for (int m = 0; m < 4; ++m)
#pragma unroll
                    for (int r = 0; r < 4; ++r)
                        if (kv0 + 32 * (m >> 1) + 8 * quad + 4 * (m & 1) + r > qrow)
                            sa[m][r] = -3e38f;
            }
            float rs = 0.f;
#pragma unroll
            for (int m = 0; m < 4; ++m)
#pragma unroll
                for (int r = 0; r < 4; ++r) {
                    float pe = exp2f(sa[m][r]);
                    sa[m][r] = pe;
                    rs += pe;
                }
            rs += __shfl_xor(rs, 16, 64);
            rs += __shfl_xor(rs, 32, 64);
            lrun += rs;

            // P -> bf16; pk[2ks2],pk[2ks2+1] form the K=32 B-frag directly
            uint2 pk[4];
#pragma unroll
            for (int m = 0; m < 4; ++m) pk[m] = pack4(sa[m]);
            bfrag pb[2];
            pb[0] = __builtin_bit_cast(bfrag, (uint4){pk[0].x, pk[0].y, pk[1].x, pk[1].y});
            pb[1] = __builtin_bit_cast(bfrag, (uint4){pk[2].x, pk[2].y, pk[3].x, pk[3].y});

            // O^T += V^T * P^T : K=32 MFMA, A = V^T b128 (gemm-proven conflict-free)
            __builtin_amdgcn_s_setprio(1);
#pragma unroll
            for (int ks2 = 0; ks2 < 2; ++ks2) {
#pragma unroll
                for (int dt = 0; dt < 8; ++dt) {
                    int d = dt * 16 + l16;
                    bfrag vf = *(const bfrag*)&VsT[cur][(d * 8 + ((ks2 * 4 + quad) ^ (d & 7))) * 8];
                    o[dt] = __builtin_amdgcn_mfma_f32_16x16x32_bf16(vf, pb[ks2], o[dt], 0, 0, 0);
                }
            }
            __builtin_amdgcn_s_setprio(0);
        }
        asm volatile("" ::: "memory");
        // no end barrier: next iteration's start barrier provides the rendezvous
    }

    // epilogue: normalize, pack, store 8B per (lane, dtile)
    float inv = 1.0f / lrun;
    size_t orow = (rowBase + qrow) * 2048 + h * 128 + quad * 4;
#pragma unroll
    for (int dt = 0; dt < 8; ++dt) {
        float a0 = o[dt][0] * inv, a1 = o[dt][1] * inv;
        float a2 = o[dt][2] * inv, a3 = o[dt][3] * inv;
        uint2 pko;
        asm("v_cvt_pk_bf16_f32 %0, %1, %2" : "=v"(pko.x) : "v"(a0), "v"(a1));
        asm("v_cvt_pk_bf16_f32 %0, %1, %2" : "=v"(pko.y) : "v"(a2), "v"(a3));
        *(uint2*)(out + orow + dt * 16) = pko;
    }
}

extern "C" void kernel_launch(void* const* d_in, const int* in_sizes, int n_in,
                              void* d_out, int out_size, void* d_ws, size_t ws_size,
                              hipStream_t stream) {
    const float* hs   = (const float*)d_in[0];
    const float* cosb = (const float*)d_in[1];
    const float* sinb = (const float*)d_in[2];
    const float* Wq = (const float*)d_in[4];
    const float* Wk = (const float*)d_in[5];
    const float* Wv = (const float*)d_in[6];
    const float* Wo = (const float*)d_in[7];
    const float* qw = (const float*)d_in[8];
    const float* kw = (const float*)d_in[9];
    float* out = (float*)d_out;

    char* ws = (char*)d_ws;
    u16* hsb   = (u16*)(ws + 0);          // 16 MB: hs bf16; later reused as attn-out bf16
    u16* wqkvT = (u16*)(ws + 16777216);   // 12 MB
    u16* woT   = (u16*)(ws + 29360128);   // 8 MB
    u16* qkv   = (u16*)(ws + 37748736);   // 24 MB
    u16* vT    = (u16*)(ws + 62914560);   // 4 MB

    dim3 tb(32, 8);
    cvt_f32_bf16<<<8192, 256, 0, stream>>>(hs, hsb, 2097152);
    transpose_cvt<<<dim3(64, 64), tb, 0, stream>>>(Wq, wqkvT, 2048, 2048);
    transpose_cvt<<<dim3(16, 64), tb, 0, stream>>>(Wk, wqkvT + (size_t)2048 * 2048, 2048, 512);
    transpose_cvt<<<dim3(16, 64), tb, 0, stream>>>(Wv, wqkvT + (size_t)2560 * 2048, 2048, 512);
    transpose_cvt<<<dim3(64, 64), tb, 0, stream>>>(Wo, woT, 2048, 2048);

    // QKV projection: M=4096, N=3072, K=2048 -> BN=192: 16x16 = 256 blocks (R9-proven)
    gemm_p4<192, u16><<<dim3(16, 16), 512, 0, stream>>>(hsb, wqkvT, qkv, 2048, 3072);

    rmsrope<<<20480, 256, 0, stream>>>(qkv, cosb, sinb, qw, kw);
    transpose_v<<<dim3(4, 64, 8), tb, 0, stream>>>(qkv, vT);

    attn_kernel<<<dim3(32, 16), 512, 0, stream>>>(qkv, vT, hsb);

    // O projection: M=4096, N=2048, K=2048 -> BN=128: 16x16 = 256 blocks
    gemm_p4<128, float><<<dim3(16, 16), 512, 0, stream>>>(hsb, woT, out, 2048, 2048);
}